// Round 5
// baseline (53.360 us; speedup 1.0000x reference)
//
#include <hip/hip_runtime.h>

// BilinearSampler: B=128, H=256, W=256, C=3
// Input row layout: [theta(6) | image(H*W*C)] per batch, f32.
//
// r4 established: adaptive lane direction (walk lanes along the output dim
// with smaller image-row step) cut wall 52.6->41.5us. rocprof showed
// occupancy collapsed to 39% (25KB static LDS charged to every block) while
// 96% of gather bytes are L1/L2 hits -> ~200cy latency chains, under-covered.
//
// Round 5: halve LDS (case-B tile staged/stored in two 16-col phases:
// 25088 -> 12800 B) + __launch_bounds__(256,8) -> up to 8 blocks/CU.
// Per-pixel sampling arithmetic identical to the passing r3/r4 kernels.

constexpr int BB = 128;
constexpr int HH = 256;
constexpr int WW = 256;
constexpr int CC = 3;
constexpr long long IMG_ELEMS = (long long)HH * WW * CC;   // 196608
constexpr long long ROW_ELEMS = 6 + IMG_ELEMS;             // 196614
constexpr int NWG = BB * 32;                               // 4096 blocks, %8==0
constexpr int LDSW = 50;  // 16 px = 48 floats + 2 pad; even -> 8B-aligned pairs

typedef float f32x4 __attribute__((ext_vector_type(4)));
typedef float f32x2 __attribute__((ext_vector_type(2)));
typedef f32x4 f32x4_a4 __attribute__((aligned(4)));
typedef f32x2 f32x2_a4 __attribute__((aligned(4)));
struct F3 { float v[3]; };

__device__ __forceinline__ void sample_px(
    const float* __restrict__ img,
    float t00, float t01, float t02, float t10, float t11, float t12,
    int w, int h, float o[3])
{
    const float xt = -1.0f + (2.0f / (WW - 1)) * (float)w;
    const float yt = -1.0f + (2.0f / (HH - 1)) * (float)h;
    const float x_s = t00 * xt + t01 * yt + t02;
    const float y_s = t10 * xt + t11 * yt + t12;
    const float x = 0.5f * (x_s + 1.0f) * (float)(WW - 1);
    const float y = 0.5f * (y_s + 1.0f) * (float)(HH - 1);

    const int x0 = (int)floorf(x);
    const int y0 = (int)floorf(y);
    const int x0c = min(max(x0,     0), WW - 1);
    const int x1c = min(max(x0 + 1, 0), WW - 1);
    const int y0c = min(max(y0,     0), HH - 1);
    const int y1c = min(max(y0 + 1, 0), HH - 1);
    const int xp  = min(max(x0, 0), WW - 2);   // pair-load base column

    const float* plo = img + (y0c * WW + xp) * CC;
    const float* phi = img + (y1c * WW + xp) * CC;
    const f32x4_a4 lo4 = *reinterpret_cast<const f32x4_a4*>(plo);
    const f32x2_a4 lo2 = *reinterpret_cast<const f32x2_a4*>(plo + 4);
    const f32x4_a4 hi4 = *reinterpret_cast<const f32x4_a4*>(phi);
    const f32x2_a4 hi2 = *reinterpret_cast<const f32x2_a4*>(phi + 4);

    const float loP0[3] = {lo4.x, lo4.y, lo4.z};
    const float loP1[3] = {lo4.w, lo2.x, lo2.y};
    const float hiP0[3] = {hi4.x, hi4.y, hi4.z};
    const float hiP1[3] = {hi4.w, hi2.x, hi2.y};

    const bool selA = (x0 > WW - 2);  // Ia/Ib = P1 only on right clip
    const bool selC = (x0 >= 0);      // Ic/Id = P1 except on left clip

    const float x0f = (float)x0c, x1f = (float)x1c;
    const float y0f = (float)y0c, y1f = (float)y1c;
    const float wa = (x1f - x) * (y1f - y);
    const float wb = (x1f - x) * (y - y0f);
    const float wc = (x - x0f) * (y1f - y);
    const float wd = (x - x0f) * (y - y0f);

    #pragma unroll
    for (int c = 0; c < 3; ++c) {
        const float Ia = selA ? loP1[c] : loP0[c];
        const float Ib = selA ? hiP1[c] : hiP0[c];
        const float Ic = selC ? loP1[c] : loP0[c];
        const float Id = selC ? hiP1[c] : hiP0[c];
        o[c] = wa * Ia + wb * Ib + wc * Ic + wd * Id;
    }
}

__global__ __launch_bounds__(256, 8) void bilinear_sampler_kernel(
    const float* __restrict__ in, float* __restrict__ out)
{
    __shared__ float lds[64 * LDSW];   // 12800 B

    // XCD-chunked bijective swizzle (4096 % 8 == 0).
    const int bid = blockIdx.x;
    const int swz = (bid & 7) * (NWG >> 3) + (bid >> 3);
    const int b    = swz >> 5;        // batch
    const int beta = swz & 31;        // block-within-batch

    const float* __restrict__ base = in + (long long)b * ROW_ELEMS;
    const float t00 = base[0], t01 = base[1], t02 = base[2];
    const float t10 = base[3], t11 = base[4], t12 = base[5];
    const float* __restrict__ img = base + 6;
    float* __restrict__ outb = out + (long long)b * IMG_ELEMS;

    const int tid = threadIdx.x;

    if (fabsf(t10) <= fabsf(t11)) {
        // ---- Case A: lanes along w (y-step per lane = t10 = min). ----
        // Tile: 8 rows x 256 cols. Stores directly coalesced.
        const int h0 = beta * 8;
        const int w  = tid;
        #pragma unroll
        for (int r = 0; r < 8; ++r) {
            float o[3];
            sample_px(img, t00, t01, t02, t10, t11, t12, w, h0 + r, o);
            F3 s; s.v[0] = o[0]; s.v[1] = o[1]; s.v[2] = o[2];
            *reinterpret_cast<F3*>(outb + ((h0 + r) * WW + w) * CC) = s;
        }
    } else {
        // ---- Case B: lanes along h (y-step per lane = t11 = min). ----
        // Tile: 64 rows x 32 cols, processed as two 16-col phases so the
        // LDS staging buffer is half the r4 size (12800 B).
        const int h0 = (beta & 3) * 64;
        const int w0 = (beta >> 2) * 32;
        const int l  = tid & 63;          // lane -> h offset
        const int v  = tid >> 6;          // wave -> col group
        #pragma unroll
        for (int hf = 0; hf < 2; ++hf) {
            const int wbase = w0 + hf * 16;
            #pragma unroll
            for (int j = 0; j < 4; ++j) {
                const int c = v * 4 + j;      // col 0..15 within phase
                float o[3];
                sample_px(img, t00, t01, t02, t10, t11, t12,
                          wbase + c, h0 + l, o);
                float* dst = &lds[l * LDSW + c * 3];
                dst[0] = o[0]; dst[1] = o[1]; dst[2] = o[2];
            }
            __syncthreads();
            // Store phase: 64 rows x 48 floats = 1536 dword-pairs.
            #pragma unroll
            for (int p = 0; p < 6; ++p) {
                const int d2 = p * 256 + tid;     // 0..1535
                const int r  = d2 / 24;
                const int k  = d2 % 24;
                const f32x2 val =
                    *reinterpret_cast<const f32x2*>(&lds[r * LDSW + k * 2]);
                *reinterpret_cast<f32x2*>(
                    outb + (h0 + r) * (WW * CC) + wbase * CC + k * 2) = val;
            }
            __syncthreads();   // lds reused by next phase
        }
    }
}

extern "C" void kernel_launch(void* const* d_in, const int* in_sizes, int n_in,
                              void* d_out, int out_size, void* d_ws, size_t ws_size,
                              hipStream_t stream)
{
    const float* in = (const float*)d_in[0];
    float* out = (float*)d_out;
    dim3 grid(NWG), block(256);
    bilinear_sampler_kernel<<<grid, block, 0, stream>>>(in, out);
}

// Round 6
// 41.520 us; speedup vs baseline: 1.2852x; 1.2852x over previous
//
#include <hip/hip_runtime.h>

// BilinearSampler: B=128, H=256, W=256, C=3
// Input row layout: [theta(6) | image(H*W*C)] per batch, f32.
//
// r4 (41.5us): adaptive lane direction + LDS-staged case-B stores. r5 lesson:
// forcing occupancy via __launch_bounds__(256,8) caused VGPR-32 spills
// (WRITE_SIZE 133MB > 98MB output = scratch traffic) and regressed.
//
// Round 6: revert to r4 structure; raise gather memory-level parallelism by
// ILP instead of TLP. Each group of 4 pixels computes all addresses and
// issues all 16 gather loads BEFORE any weight math (loads held in explicit
// vector regs), under __launch_bounds__(256,4) (128-VGPR cap, no spill).
// Per-pixel sampling arithmetic identical to the passing r3/r4/r5 kernels.

constexpr int BB = 128;
constexpr int HH = 256;
constexpr int WW = 256;
constexpr int CC = 3;
constexpr long long IMG_ELEMS = (long long)HH * WW * CC;   // 196608
constexpr long long ROW_ELEMS = 6 + IMG_ELEMS;             // 196614
constexpr int NWG = BB * 32;                               // 4096 blocks, %8==0
constexpr int LDSW = 98;  // 32 px = 96 floats + 2 pad (case-B staging row)

typedef float f32x4 __attribute__((ext_vector_type(4)));
typedef float f32x2 __attribute__((ext_vector_type(2)));
typedef f32x4 f32x4_a4 __attribute__((aligned(4)));
typedef f32x2 f32x2_a4 __attribute__((aligned(4)));
struct F3 { float v[3]; };

struct Coord {
    const float* plo;
    const float* phi;
    int x0;
    float x, y;
    float x0f, x1f, y0f, y1f;
};

__device__ __forceinline__ Coord make_coord(
    const float* __restrict__ img,
    float t00, float t01, float t02, float t10, float t11, float t12,
    int w, int h)
{
    Coord q;
    const float xt = -1.0f + (2.0f / (WW - 1)) * (float)w;
    const float yt = -1.0f + (2.0f / (HH - 1)) * (float)h;
    const float x_s = t00 * xt + t01 * yt + t02;
    const float y_s = t10 * xt + t11 * yt + t12;
    q.x = 0.5f * (x_s + 1.0f) * (float)(WW - 1);
    q.y = 0.5f * (y_s + 1.0f) * (float)(HH - 1);

    q.x0 = (int)floorf(q.x);
    const int y0 = (int)floorf(q.y);
    const int x0c = min(max(q.x0,     0), WW - 1);
    const int x1c = min(max(q.x0 + 1, 0), WW - 1);
    const int y0c = min(max(y0,       0), HH - 1);
    const int y1c = min(max(y0 + 1,   0), HH - 1);
    const int xp  = min(max(q.x0, 0), WW - 2);   // pair-load base column

    q.plo = img + (y0c * WW + xp) * CC;
    q.phi = img + (y1c * WW + xp) * CC;
    q.x0f = (float)x0c; q.x1f = (float)x1c;
    q.y0f = (float)y0c; q.y1f = (float)y1c;
    return q;
}

__device__ __forceinline__ void combine(
    const Coord& q, f32x4 lo4, f32x2 lo2, f32x4 hi4, f32x2 hi2, float o[3])
{
    const float loP0[3] = {lo4.x, lo4.y, lo4.z};
    const float loP1[3] = {lo4.w, lo2.x, lo2.y};
    const float hiP0[3] = {hi4.x, hi4.y, hi4.z};
    const float hiP1[3] = {hi4.w, hi2.x, hi2.y};

    const bool selA = (q.x0 > WW - 2);  // Ia/Ib = P1 only on right clip
    const bool selC = (q.x0 >= 0);      // Ic/Id = P1 except on left clip

    const float wa = (q.x1f - q.x) * (q.y1f - q.y);
    const float wb = (q.x1f - q.x) * (q.y - q.y0f);
    const float wc = (q.x - q.x0f) * (q.y1f - q.y);
    const float wd = (q.x - q.x0f) * (q.y - q.y0f);

    #pragma unroll
    for (int c = 0; c < 3; ++c) {
        const float Ia = selA ? loP1[c] : loP0[c];
        const float Ib = selA ? hiP1[c] : hiP0[c];
        const float Ic = selC ? loP1[c] : loP0[c];
        const float Id = selC ? hiP1[c] : hiP0[c];
        o[c] = wa * Ia + wb * Ib + wc * Ic + wd * Id;
    }
}

__global__ __launch_bounds__(256, 4) void bilinear_sampler_kernel(
    const float* __restrict__ in, float* __restrict__ out)
{
    __shared__ float lds[64 * LDSW];   // 25088 B (case-B staging)

    // XCD-chunked bijective swizzle (4096 % 8 == 0).
    const int bid = blockIdx.x;
    const int swz = (bid & 7) * (NWG >> 3) + (bid >> 3);
    const int b    = swz >> 5;        // batch
    const int beta = swz & 31;        // block-within-batch

    const float* __restrict__ base = in + (long long)b * ROW_ELEMS;
    const float t00 = base[0], t01 = base[1], t02 = base[2];
    const float t10 = base[3], t11 = base[4], t12 = base[5];
    const float* __restrict__ img = base + 6;
    float* __restrict__ outb = out + (long long)b * IMG_ELEMS;

    const int tid = threadIdx.x;

    if (fabsf(t10) <= fabsf(t11)) {
        // ---- Case A: lanes along w (y-step per lane = t10 = min). ----
        // Tile: 8 rows x 256 cols; stores directly coalesced.
        const int h0 = beta * 8;
        const int w  = tid;
        #pragma unroll
        for (int g = 0; g < 2; ++g) {
            Coord q[4];
            f32x4 lo4[4], hi4[4];
            f32x2 lo2[4], hi2[4];
            // Phase 1: addresses + issue all 16 loads (held in regs).
            #pragma unroll
            for (int j = 0; j < 4; ++j) {
                const int h = h0 + g * 4 + j;
                q[j] = make_coord(img, t00, t01, t02, t10, t11, t12, w, h);
                lo4[j] = *reinterpret_cast<const f32x4_a4*>(q[j].plo);
                lo2[j] = *reinterpret_cast<const f32x2_a4*>(q[j].plo + 4);
                hi4[j] = *reinterpret_cast<const f32x4_a4*>(q[j].phi);
                hi2[j] = *reinterpret_cast<const f32x2_a4*>(q[j].phi + 4);
            }
            // Phase 2: weights + combine + store.
            #pragma unroll
            for (int j = 0; j < 4; ++j) {
                const int h = h0 + g * 4 + j;
                float o[3];
                combine(q[j], lo4[j], lo2[j], hi4[j], hi2[j], o);
                F3 s; s.v[0] = o[0]; s.v[1] = o[1]; s.v[2] = o[2];
                *reinterpret_cast<F3*>(outb + (h * WW + w) * CC) = s;
            }
        }
    } else {
        // ---- Case B: lanes along h (y-step per lane = t11 = min). ----
        // Tile: 64 rows x 32 cols; staged in LDS, stored coalesced.
        const int h0 = (beta & 3) * 64;
        const int w0 = (beta >> 2) * 32;
        const int l  = tid & 63;          // lane -> h offset
        const int v  = tid >> 6;          // wave -> col group (8 cols)
        #pragma unroll
        for (int g = 0; g < 2; ++g) {
            Coord q[4];
            f32x4 lo4[4], hi4[4];
            f32x2 lo2[4], hi2[4];
            #pragma unroll
            for (int j = 0; j < 4; ++j) {
                const int c = v * 8 + g * 4 + j;   // col 0..31
                q[j] = make_coord(img, t00, t01, t02, t10, t11, t12,
                                  w0 + c, h0 + l);
                lo4[j] = *reinterpret_cast<const f32x4_a4*>(q[j].plo);
                lo2[j] = *reinterpret_cast<const f32x2_a4*>(q[j].plo + 4);
                hi4[j] = *reinterpret_cast<const f32x4_a4*>(q[j].phi);
                hi2[j] = *reinterpret_cast<const f32x2_a4*>(q[j].phi + 4);
            }
            #pragma unroll
            for (int j = 0; j < 4; ++j) {
                const int c = v * 8 + g * 4 + j;
                float o[3];
                combine(q[j], lo4[j], lo2[j], hi4[j], hi2[j], o);
                float* dst = &lds[l * LDSW + c * 3];
                dst[0] = o[0]; dst[1] = o[1]; dst[2] = o[2];
            }
        }
        __syncthreads();
        // Store phase: tile row r = 32 px = 96 dwords = 48 dword-pairs.
        #pragma unroll
        for (int p = 0; p < 12; ++p) {
            const int d2 = p * 256 + tid;     // pair index 0..3071
            const int r  = d2 / 48;
            const int k  = d2 % 48;
            const f32x2 val = *reinterpret_cast<const f32x2*>(&lds[r * LDSW + k * 2]);
            *reinterpret_cast<f32x2*>(
                outb + (h0 + r) * (WW * CC) + w0 * CC + k * 2) = val;
        }
    }
}

extern "C" void kernel_launch(void* const* d_in, const int* in_sizes, int n_in,
                              void* d_out, int out_size, void* d_ws, size_t ws_size,
                              hipStream_t stream)
{
    const float* in = (const float*)d_in[0];
    float* out = (float*)d_out;
    dim3 grid(NWG), block(256);
    bilinear_sampler_kernel<<<grid, block, 0, stream>>>(in, out);
}

// Round 7
// 40.806 us; speedup vs baseline: 1.3076x; 1.0175x over previous
//
#include <hip/hip_runtime.h>

// BilinearSampler: B=128, H=256, W=256, C=3
// Input row layout: [theta(6) | image(H*W*C)] per batch, f32.
//
// r4 (41.5us): adaptive lane direction + LDS-staged case-B stores.
// r6 null EXPLAINED: VGPR stayed 40 -> compiler sank the grouped loads back
// to use sites; the 16-deep ILP was never emitted. r5 lesson: never cap regs.
//
// Round 7: compiler-proof deep MLP. Each thread computes all 8 pixel
// addresses and issues all 32 gather loads, then an empty asm volatile
// consumes every loaded value -- forcing all 32 results simultaneously live
// (the compiler cannot re-serialize). No launch-bounds reg cap.
// Per-pixel sampling arithmetic identical to the passing r3-r6 kernels.

constexpr int BB = 128;
constexpr int HH = 256;
constexpr int WW = 256;
constexpr int CC = 3;
constexpr long long IMG_ELEMS = (long long)HH * WW * CC;   // 196608
constexpr long long ROW_ELEMS = 6 + IMG_ELEMS;             // 196614
constexpr int NWG = BB * 32;                               // 4096 blocks, %8==0
constexpr int LDSW = 98;  // 32 px = 96 floats + 2 pad (case-B staging row)

typedef float f32x4 __attribute__((ext_vector_type(4)));
typedef float f32x2 __attribute__((ext_vector_type(2)));
typedef f32x4 f32x4_a4 __attribute__((aligned(4)));
typedef f32x2 f32x2_a4 __attribute__((aligned(4)));
struct F3 { float v[3]; };

struct Coord {
    const float* plo;
    const float* phi;
    int x0;
    float x, y;
    float x0f, x1f, y0f, y1f;
};

__device__ __forceinline__ Coord make_coord(
    const float* __restrict__ img,
    float t00, float t01, float t02, float t10, float t11, float t12,
    int w, int h)
{
    Coord q;
    const float xt = -1.0f + (2.0f / (WW - 1)) * (float)w;
    const float yt = -1.0f + (2.0f / (HH - 1)) * (float)h;
    const float x_s = t00 * xt + t01 * yt + t02;
    const float y_s = t10 * xt + t11 * yt + t12;
    q.x = 0.5f * (x_s + 1.0f) * (float)(WW - 1);
    q.y = 0.5f * (y_s + 1.0f) * (float)(HH - 1);

    q.x0 = (int)floorf(q.x);
    const int y0 = (int)floorf(q.y);
    const int x0c = min(max(q.x0,     0), WW - 1);
    const int x1c = min(max(q.x0 + 1, 0), WW - 1);
    const int y0c = min(max(y0,       0), HH - 1);
    const int y1c = min(max(y0 + 1,   0), HH - 1);
    const int xp  = min(max(q.x0, 0), WW - 2);   // pair-load base column

    q.plo = img + (y0c * WW + xp) * CC;
    q.phi = img + (y1c * WW + xp) * CC;
    q.x0f = (float)x0c; q.x1f = (float)x1c;
    q.y0f = (float)y0c; q.y1f = (float)y1c;
    return q;
}

__device__ __forceinline__ void combine(
    const Coord& q, f32x4 lo4, f32x2 lo2, f32x4 hi4, f32x2 hi2, float o[3])
{
    const float loP0[3] = {lo4.x, lo4.y, lo4.z};
    const float loP1[3] = {lo4.w, lo2.x, lo2.y};
    const float hiP0[3] = {hi4.x, hi4.y, hi4.z};
    const float hiP1[3] = {hi4.w, hi2.x, hi2.y};

    const bool selA = (q.x0 > WW - 2);  // Ia/Ib = P1 only on right clip
    const bool selC = (q.x0 >= 0);      // Ic/Id = P1 except on left clip

    const float wa = (q.x1f - q.x) * (q.y1f - q.y);
    const float wb = (q.x1f - q.x) * (q.y - q.y0f);
    const float wc = (q.x - q.x0f) * (q.y1f - q.y);
    const float wd = (q.x - q.x0f) * (q.y - q.y0f);

    #pragma unroll
    for (int c = 0; c < 3; ++c) {
        const float Ia = selA ? loP1[c] : loP0[c];
        const float Ib = selA ? hiP1[c] : hiP0[c];
        const float Ic = selC ? loP1[c] : loP0[c];
        const float Id = selC ? hiP1[c] : hiP0[c];
        o[c] = wa * Ia + wb * Ib + wc * Ic + wd * Id;
    }
}

__global__ __launch_bounds__(256) void bilinear_sampler_kernel(
    const float* __restrict__ in, float* __restrict__ out)
{
    __shared__ float lds[64 * LDSW];   // 25088 B (case-B staging)

    // XCD-chunked bijective swizzle (4096 % 8 == 0).
    const int bid = blockIdx.x;
    const int swz = (bid & 7) * (NWG >> 3) + (bid >> 3);
    const int b    = swz >> 5;        // batch
    const int beta = swz & 31;        // block-within-batch

    const float* __restrict__ base = in + (long long)b * ROW_ELEMS;
    const float t00 = base[0], t01 = base[1], t02 = base[2];
    const float t10 = base[3], t11 = base[4], t12 = base[5];
    const float* __restrict__ img = base + 6;
    float* __restrict__ outb = out + (long long)b * IMG_ELEMS;

    const int tid = threadIdx.x;

    if (fabsf(t10) <= fabsf(t11)) {
        // ---- Case A: lanes along w (y-step per lane = t10 = min). ----
        // Tile: 8 rows x 256 cols; stores directly coalesced.
        const int h0 = beta * 8;
        const int w  = tid;

        Coord q[8];
        f32x4 lo4[8], hi4[8];
        f32x2 lo2[8], hi2[8];
        // Phase 1: all addresses + all 32 loads issued back-to-back.
        #pragma unroll
        for (int j = 0; j < 8; ++j) {
            q[j] = make_coord(img, t00, t01, t02, t10, t11, t12, w, h0 + j);
            lo4[j] = *reinterpret_cast<const f32x4_a4*>(q[j].plo);
            lo2[j] = *reinterpret_cast<const f32x2_a4*>(q[j].plo + 4);
            hi4[j] = *reinterpret_cast<const f32x4_a4*>(q[j].phi);
            hi2[j] = *reinterpret_cast<const f32x2_a4*>(q[j].phi + 4);
        }
        // Force all 32 results simultaneously live: compiler cannot sink
        // loads to their uses / serialize through a small reg window.
        #pragma unroll
        for (int j = 0; j < 8; ++j)
            asm volatile("" :: "v"(lo4[j]), "v"(lo2[j]), "v"(hi4[j]), "v"(hi2[j]));
        // Phase 2: weights + combine + store.
        #pragma unroll
        for (int j = 0; j < 8; ++j) {
            float o[3];
            combine(q[j], lo4[j], lo2[j], hi4[j], hi2[j], o);
            F3 s; s.v[0] = o[0]; s.v[1] = o[1]; s.v[2] = o[2];
            *reinterpret_cast<F3*>(outb + ((h0 + j) * WW + w) * CC) = s;
        }
    } else {
        // ---- Case B: lanes along h (y-step per lane = t11 = min). ----
        // Tile: 64 rows x 32 cols; staged in LDS, stored coalesced.
        const int h0 = (beta & 3) * 64;
        const int w0 = (beta >> 2) * 32;
        const int l  = tid & 63;          // lane -> h offset
        const int v  = tid >> 6;          // wave -> col group (8 cols)

        Coord q[8];
        f32x4 lo4[8], hi4[8];
        f32x2 lo2[8], hi2[8];
        #pragma unroll
        for (int j = 0; j < 8; ++j) {
            const int c = v * 8 + j;      // col 0..31
            q[j] = make_coord(img, t00, t01, t02, t10, t11, t12,
                              w0 + c, h0 + l);
            lo4[j] = *reinterpret_cast<const f32x4_a4*>(q[j].plo);
            lo2[j] = *reinterpret_cast<const f32x2_a4*>(q[j].plo + 4);
            hi4[j] = *reinterpret_cast<const f32x4_a4*>(q[j].phi);
            hi2[j] = *reinterpret_cast<const f32x2_a4*>(q[j].phi + 4);
        }
        #pragma unroll
        for (int j = 0; j < 8; ++j)
            asm volatile("" :: "v"(lo4[j]), "v"(lo2[j]), "v"(hi4[j]), "v"(hi2[j]));
        #pragma unroll
        for (int j = 0; j < 8; ++j) {
            const int c = v * 8 + j;
            float o[3];
            combine(q[j], lo4[j], lo2[j], hi4[j], hi2[j], o);
            float* dst = &lds[l * LDSW + c * 3];
            dst[0] = o[0]; dst[1] = o[1]; dst[2] = o[2];
        }
        __syncthreads();
        // Store phase: tile row r = 32 px = 96 dwords = 48 dword-pairs.
        #pragma unroll
        for (int p = 0; p < 12; ++p) {
            const int d2 = p * 256 + tid;     // pair index 0..3071
            const int r  = d2 / 48;
            const int k  = d2 % 48;
            const f32x2 val = *reinterpret_cast<const f32x2*>(&lds[r * LDSW + k * 2]);
            *reinterpret_cast<f32x2*>(
                outb + (h0 + r) * (WW * CC) + w0 * CC + k * 2) = val;
        }
    }
}

extern "C" void kernel_launch(void* const* d_in, const int* in_sizes, int n_in,
                              void* d_out, int out_size, void* d_ws, size_t ws_size,
                              hipStream_t stream)
{
    const float* in = (const float*)d_in[0];
    float* out = (float*)d_out;
    dim3 grid(NWG), block(256);
    bilinear_sampler_kernel<<<grid, block, 0, stream>>>(in, out);
}

// Round 8
// 38.795 us; speedup vs baseline: 1.3754x; 1.0519x over previous
//
#include <hip/hip_runtime.h>

// BilinearSampler: B=128, H=256, W=256, C=3
// Input row layout: [theta(6) | image(H*W*C)] per batch, f32.
//
// r7 established (by elimination): cost = per-instruction distinct 64B
// line-requests in the TA (forcing 32-deep MLP with VGPR evidence changed
// nothing). The 4-instruction-per-pixel gather (x4+x2 per row) charges each
// image row ~4x. Round 8: LANE-PAIR SPLIT -- lane 2i loads the x0c column
// (dwordx3), lane 2i+1 loads x1c; each computes its partial
// w_lo*v_lo + w_hi*v_hi; one __shfl_xor(.,1) per channel sums the pair.
// One 64-lane instruction now serves each row-level of 32 pixels:
// ~36% fewer TA line-requests on the dominant gather term.
// Clip/weight math identical to r3-r7 (only 4-term sum reassociation).

constexpr int BB = 128;
constexpr int HH = 256;
constexpr int WW = 256;
constexpr int CC = 3;
constexpr long long IMG_ELEMS = (long long)HH * WW * CC;   // 196608
constexpr long long ROW_ELEMS = 6 + IMG_ELEMS;             // 196614
constexpr int NWG = BB * 32;                               // 4096 blocks, %8==0
constexpr int LDSW = 98;  // 32 px = 96 floats + 2 pad (case-B staging row)

typedef float f32x2 __attribute__((ext_vector_type(2)));
struct F3 { float v[3]; };

struct SCoord {
    int ylo, yhi;      // clipped rows
    int col0, col1;    // clipped x0c, x1c
    float wlo0, whi0;  // weights for the x0c column (wa, wb)
    float wlo1, whi1;  // weights for the x1c column (wc, wd)
};

__device__ __forceinline__ SCoord make_scoord(
    float t00, float t01, float t02, float t10, float t11, float t12,
    int w, int h)
{
    SCoord q;
    const float xt = -1.0f + (2.0f / (WW - 1)) * (float)w;
    const float yt = -1.0f + (2.0f / (HH - 1)) * (float)h;
    const float x_s = t00 * xt + t01 * yt + t02;
    const float y_s = t10 * xt + t11 * yt + t12;
    const float x = 0.5f * (x_s + 1.0f) * (float)(WW - 1);
    const float y = 0.5f * (y_s + 1.0f) * (float)(HH - 1);

    const int x0 = (int)floorf(x);
    const int y0 = (int)floorf(y);
    q.col0 = min(max(x0,     0), WW - 1);
    q.col1 = min(max(x0 + 1, 0), WW - 1);
    q.ylo  = min(max(y0,     0), HH - 1);
    q.yhi  = min(max(y0 + 1, 0), HH - 1);

    const float x0f = (float)q.col0, x1f = (float)q.col1;
    const float y0f = (float)q.ylo,  y1f = (float)q.yhi;
    q.wlo0 = (x1f - x) * (y1f - y);   // wa  (Ia = [ylo][col0])
    q.whi0 = (x1f - x) * (y - y0f);   // wb  (Ib = [yhi][col0])
    q.wlo1 = (x - x0f) * (y1f - y);   // wc  (Ic = [ylo][col1])
    q.whi1 = (x - x0f) * (y - y0f);   // wd  (Id = [yhi][col1])
    return q;
}

// Per-phase pixel work shared by both cases: lane pair (2i, 2i+1) jointly
// computes pixel's 3 channels; returns the summed value (valid in all lanes).
__device__ __forceinline__ void pair_sample(
    const float* __restrict__ img, const SCoord& q, int odd, float o[3])
{
    const int mycol = odd ? q.col1 : q.col0;
    const float wlo = odd ? q.wlo1 : q.wlo0;
    const float whi = odd ? q.whi1 : q.whi0;
    const F3 vlo = *reinterpret_cast<const F3*>(img + (q.ylo * WW + mycol) * CC);
    const F3 vhi = *reinterpret_cast<const F3*>(img + (q.yhi * WW + mycol) * CC);
    #pragma unroll
    for (int c = 0; c < 3; ++c) {
        const float part = wlo * vlo.v[c] + whi * vhi.v[c];
        o[c] = part + __shfl_xor(part, 1, 64);
    }
}

__global__ __launch_bounds__(256) void bilinear_sampler_kernel(
    const float* __restrict__ in, float* __restrict__ out)
{
    __shared__ float lds[64 * LDSW];   // 25088 B (case-B staging)

    // XCD-chunked bijective swizzle (4096 % 8 == 0).
    const int bid = blockIdx.x;
    const int swz = (bid & 7) * (NWG >> 3) + (bid >> 3);
    const int b    = swz >> 5;        // batch
    const int beta = swz & 31;        // block-within-batch

    const float* __restrict__ base = in + (long long)b * ROW_ELEMS;
    const float t00 = base[0], t01 = base[1], t02 = base[2];
    const float t10 = base[3], t11 = base[4], t12 = base[5];
    const float* __restrict__ img = base + 6;
    float* __restrict__ outb = out + (long long)b * IMG_ELEMS;

    const int tid = threadIdx.x;
    const int v   = tid >> 6;         // wave index 0..3
    const int l   = tid & 63;         // lane
    const int i   = l >> 1;           // pair index 0..31
    const int odd = l & 1;

    if (fabsf(t10) <= fabsf(t11)) {
        // ---- Case A: pixel runs along w (y-step per pair = t10 = min). ----
        // Block tile: 256w x 8h. Wave v owns rows {h0+2v, h0+2v+1}.
        const int h0 = beta * 8;
        #pragma unroll 2
        for (int f = 0; f < 16; ++f) {
            const int row = h0 + 2 * v + (f >> 3);
            const int wpx = ((f & 7) << 5) + i;
            const SCoord q = make_scoord(t00, t01, t02, t10, t11, t12, wpx, row);
            float o[3];
            pair_sample(img, q, odd, o);
            if (!odd) {
                F3 s; s.v[0] = o[0]; s.v[1] = o[1]; s.v[2] = o[2];
                *reinterpret_cast<F3*>(outb + (row * WW + wpx) * CC) = s;
            }
        }
    } else {
        // ---- Case B: pixel runs along h (y-step per pair = t11 = min). ----
        // Block tile: 32w x 64h. Wave v owns cols {w0+8v .. w0+8v+7}.
        const int h0 = (beta & 3) * 64;
        const int w0 = (beta >> 2) * 32;
        #pragma unroll 2
        for (int f = 0; f < 16; ++f) {
            const int cpx  = 8 * v + (f >> 1);          // block-local col 0..31
            const int hloc = ((f & 1) << 5) + i;        // block-local row 0..63
            const SCoord q = make_scoord(t00, t01, t02, t10, t11, t12,
                                         w0 + cpx, h0 + hloc);
            float o[3];
            pair_sample(img, q, odd, o);
            if (!odd) {
                float* dst = &lds[hloc * LDSW + cpx * 3];
                dst[0] = o[0]; dst[1] = o[1]; dst[2] = o[2];
            }
        }
        __syncthreads();
        // Store phase: tile row r = 32 px = 96 dwords = 48 dword-pairs.
        #pragma unroll
        for (int p = 0; p < 12; ++p) {
            const int d2 = p * 256 + tid;     // pair index 0..3071
            const int r  = d2 / 48;
            const int k  = d2 % 48;
            const f32x2 val = *reinterpret_cast<const f32x2*>(&lds[r * LDSW + k * 2]);
            *reinterpret_cast<f32x2*>(
                outb + (h0 + r) * (WW * CC) + w0 * CC + k * 2) = val;
        }
    }
}

extern "C" void kernel_launch(void* const* d_in, const int* in_sizes, int n_in,
                              void* d_out, int out_size, void* d_ws, size_t ws_size,
                              hipStream_t stream)
{
    const float* in = (const float*)d_in[0];
    float* out = (float*)d_out;
    dim3 grid(NWG), block(256);
    bilinear_sampler_kernel<<<grid, block, 0, stream>>>(in, out);
}

// Round 9
// 38.531 us; speedup vs baseline: 1.3849x; 1.0068x over previous
//
#include <hip/hip_runtime.h>

// BilinearSampler: B=128, H=256, W=256, C=3
// Input row layout: [theta(6) | image(H*W*C)] per batch, f32.
//
// r8 post-mortem: lane-pair split cut line-requests but doubled VALU/px
// (32 px/instr instead of 64) -> pipes re-balanced, only -5%. Current state:
// TA lines ~14us, VALU ~25us, stores ~3us, HBM floor 19us, wall 38.8us.
//
// Round 9:
//  (a) direction metric = per-instruction line estimate 32|ty| + 6|tx|
//      (rows weighted by walk length, x-span by 12B/64B), not just |ty|.
//  (b) float-domain clamps via fminf/fmaxf -> v_med3_f32 (bit-identical
//      values; kills the int-clamp/double-convert chain, ~8 VALU/px).
// Everything else identical to the passing r8 kernel.

constexpr int BB = 128;
constexpr int HH = 256;
constexpr int WW = 256;
constexpr int CC = 3;
constexpr long long IMG_ELEMS = (long long)HH * WW * CC;   // 196608
constexpr long long ROW_ELEMS = 6 + IMG_ELEMS;             // 196614
constexpr int NWG = BB * 32;                               // 4096 blocks, %8==0
constexpr int LDSW = 98;  // 32 px = 96 floats + 2 pad (case-B staging row)

typedef float f32x2 __attribute__((ext_vector_type(2)));
struct F3 { float v[3]; };

struct SCoord {
    int ylo, yhi;      // clipped rows
    int col0, col1;    // clipped x0c, x1c
    float wlo0, whi0;  // weights for the x0c column (wa, wb)
    float wlo1, whi1;  // weights for the x1c column (wc, wd)
};

__device__ __forceinline__ SCoord make_scoord(
    float t00, float t01, float t02, float t10, float t11, float t12,
    int w, int h)
{
    SCoord q;
    const float xt = -1.0f + (2.0f / (WW - 1)) * (float)w;
    const float yt = -1.0f + (2.0f / (HH - 1)) * (float)h;
    const float x_s = t00 * xt + t01 * yt + t02;
    const float y_s = t10 * xt + t11 * yt + t12;
    const float x = 0.5f * (x_s + 1.0f) * (float)(WW - 1);
    const float y = 0.5f * (y_s + 1.0f) * (float)(HH - 1);

    // floor() results are exact integers in f32, so clamping in float is
    // bit-identical to the reference's int clamp -> v_med3_f32 each.
    const float xf = floorf(x);
    const float yf = floorf(y);
    const float x0f = fminf(fmaxf(xf,         0.0f), 255.0f);
    const float x1f = fminf(fmaxf(xf + 1.0f,  0.0f), 255.0f);
    const float y0f = fminf(fmaxf(yf,         0.0f), 255.0f);
    const float y1f = fminf(fmaxf(yf + 1.0f,  0.0f), 255.0f);

    q.col0 = (int)x0f;
    q.col1 = (int)x1f;
    q.ylo  = (int)y0f;
    q.yhi  = (int)y1f;

    q.wlo0 = (x1f - x) * (y1f - y);   // wa  (Ia = [ylo][col0])
    q.whi0 = (x1f - x) * (y - y0f);   // wb  (Ib = [yhi][col0])
    q.wlo1 = (x - x0f) * (y1f - y);   // wc  (Ic = [ylo][col1])
    q.whi1 = (x - x0f) * (y - y0f);   // wd  (Id = [yhi][col1])
    return q;
}

// Lane pair (2i, 2i+1) jointly computes one pixel's 3 channels; the summed
// value is valid in both lanes after the xor-shuffle.
__device__ __forceinline__ void pair_sample(
    const float* __restrict__ img, const SCoord& q, int odd, float o[3])
{
    const int mycol = odd ? q.col1 : q.col0;
    const float wlo = odd ? q.wlo1 : q.wlo0;
    const float whi = odd ? q.whi1 : q.whi0;
    const F3 vlo = *reinterpret_cast<const F3*>(img + (q.ylo * WW + mycol) * CC);
    const F3 vhi = *reinterpret_cast<const F3*>(img + (q.yhi * WW + mycol) * CC);
    #pragma unroll
    for (int c = 0; c < 3; ++c) {
        const float part = wlo * vlo.v[c] + whi * vhi.v[c];
        o[c] = part + __shfl_xor(part, 1, 64);
    }
}

__global__ __launch_bounds__(256) void bilinear_sampler_kernel(
    const float* __restrict__ in, float* __restrict__ out)
{
    __shared__ float lds[64 * LDSW];   // 25088 B (case-B staging)

    // XCD-chunked bijective swizzle (4096 % 8 == 0).
    const int bid = blockIdx.x;
    const int swz = (bid & 7) * (NWG >> 3) + (bid >> 3);
    const int b    = swz >> 5;        // batch
    const int beta = swz & 31;        // block-within-batch

    const float* __restrict__ base = in + (long long)b * ROW_ELEMS;
    const float t00 = base[0], t01 = base[1], t02 = base[2];
    const float t10 = base[3], t11 = base[4], t12 = base[5];
    const float* __restrict__ img = base + 6;
    float* __restrict__ outb = out + (long long)b * IMG_ELEMS;

    const int tid = threadIdx.x;
    const int v   = tid >> 6;         // wave index 0..3
    const int l   = tid & 63;         // lane
    const int i   = l >> 1;           // pair index 0..31
    const int odd = l & 1;

    // Per-instruction line estimate: rows term (32|ty|) + x-span term (6|tx|).
    const float costA = 32.0f * fabsf(t10) + 6.0f * fabsf(t00);
    const float costB = 32.0f * fabsf(t11) + 6.0f * fabsf(t01);

    if (costA <= costB) {
        // ---- Case A: pixel runs along w. ----
        // Block tile: 256w x 8h. Wave v owns rows {h0+2v, h0+2v+1}.
        const int h0 = beta * 8;
        #pragma unroll 2
        for (int f = 0; f < 16; ++f) {
            const int row = h0 + 2 * v + (f >> 3);
            const int wpx = ((f & 7) << 5) + i;
            const SCoord q = make_scoord(t00, t01, t02, t10, t11, t12, wpx, row);
            float o[3];
            pair_sample(img, q, odd, o);
            if (!odd) {
                F3 s; s.v[0] = o[0]; s.v[1] = o[1]; s.v[2] = o[2];
                *reinterpret_cast<F3*>(outb + (row * WW + wpx) * CC) = s;
            }
        }
    } else {
        // ---- Case B: pixel runs along h. ----
        // Block tile: 32w x 64h. Wave v owns cols {w0+8v .. w0+8v+7}.
        const int h0 = (beta & 3) * 64;
        const int w0 = (beta >> 2) * 32;
        #pragma unroll 2
        for (int f = 0; f < 16; ++f) {
            const int cpx  = 8 * v + (f >> 1);          // block-local col 0..31
            const int hloc = ((f & 1) << 5) + i;        // block-local row 0..63
            const SCoord q = make_scoord(t00, t01, t02, t10, t11, t12,
                                         w0 + cpx, h0 + hloc);
            float o[3];
            pair_sample(img, q, odd, o);
            if (!odd) {
                float* dst = &lds[hloc * LDSW + cpx * 3];
                dst[0] = o[0]; dst[1] = o[1]; dst[2] = o[2];
            }
        }
        __syncthreads();
        // Store phase: tile row r = 32 px = 96 dwords = 48 dword-pairs.
        #pragma unroll
        for (int p = 0; p < 12; ++p) {
            const int d2 = p * 256 + tid;     // pair index 0..3071
            const int r  = d2 / 48;
            const int k  = d2 % 48;
            const f32x2 val = *reinterpret_cast<const f32x2*>(&lds[r * LDSW + k * 2]);
            *reinterpret_cast<f32x2*>(
                outb + (h0 + r) * (WW * CC) + w0 * CC + k * 2) = val;
        }
    }
}

extern "C" void kernel_launch(void* const* d_in, const int* in_sizes, int n_in,
                              void* d_out, int out_size, void* d_ws, size_t ws_size,
                              hipStream_t stream)
{
    const float* in = (const float*)d_in[0];
    float* out = (float*)d_out;
    dim3 grid(NWG), block(256);
    bilinear_sampler_kernel<<<grid, block, 0, stream>>>(in, out);
}